// Round 4
// baseline (1384.937 us; speedup 1.0000x reference)
//
#include <hip/hip_runtime.h>
#include <math.h>

// Problem constants: B=4, C=128, O=128, H=W=128, k=3, K=9, pad=1, stride=1.
#define HWD 16384   // H*W
#define NB  4
#define NC  128
#define NO  128

typedef float f32x2 __attribute__((ext_vector_type(2)));

// w_t[r][o], r = c*9+k  (1152 x 128)
__global__ void k_transpose_wreg(const float* __restrict__ w_reg, float* __restrict__ w_t) {
    int i = blockIdx.x * 256 + threadIdx.x;           // 147456 total
    if (i >= 1152 * 128) return;
    int o = i & 127, r = i >> 7;
    w_t[r * 128 + o] = w_reg[o * 1152 + r];           // w_reg[o][c][k] flat = o*1152 + r
}

// wt_om[(c*9+k)*27 + oc]: oc 0..17 = offset weights, 18..26 = mask weights
__global__ void k_transpose_wom(const float* __restrict__ w_off, const float* __restrict__ w_mod,
                                float* __restrict__ wt_om) {
    int i = blockIdx.x * 256 + threadIdx.x;           // 31104 total
    if (i >= 1152 * 27) return;
    int oc = i % 27, r = i / 27;
    wt_om[i] = (oc < 18) ? w_off[oc * 1152 + r] : w_mod[(oc - 18) * 1152 + r];
}

// 3x3 conv producing 27 raw channels (no bias/sigmoid; applied by consumer).
// Grid: (8, 8, B*3*2). Block: 256 = 16x16 pixel tile. z -> (b, oc-group of 9, channel-half of 64).
// Accumulates into zeroed cbuf via fp32 atomicAdd (distinct addresses per block -> no contention).
__global__ __launch_bounds__(256) void k_conv_om(const float* __restrict__ x,
                                                 const float* __restrict__ wt_om,
                                                 float* __restrict__ cbuf) {
    __shared__ float xt[4 * 324];          // 4 channels x 18x18 halo tile
    int z = blockIdx.z;
    int b     = z / 6;
    int og    = z % 3;
    int chalf = (z % 6) / 3;
    int ty = blockIdx.y * 16, tx = blockIdx.x * 16;
    int tid = threadIdx.x;
    int row = tid >> 4, col = tid & 15;

    float acc[9];
#pragma unroll
    for (int j = 0; j < 9; ++j) acc[j] = 0.f;

    int cbeg = chalf * 64;
    for (int c0 = cbeg; c0 < cbeg + 64; c0 += 4) {
        __syncthreads();
        for (int i = tid; i < 1296; i += 256) {
            int ch = i / 324, rem = i - ch * 324;
            int ry = rem / 18, rx = rem - ry * 18;
            int gy = ty - 1 + ry, gx = tx - 1 + rx;
            float v = 0.f;
            if (gy >= 0 && gy < 128 && gx >= 0 && gx < 128)
                v = x[(((b << 7) + c0 + ch) << 14) + (gy << 7) + gx];
            xt[i] = v;
        }
        __syncthreads();
#pragma unroll
        for (int cc = 0; cc < 4; ++cc) {
#pragma unroll
            for (int k = 0; k < 9; ++k) {
                float xv = xt[cc * 324 + (row + k / 3) * 18 + (col + k % 3)];
                const float* wp = wt_om + ((c0 + cc) * 9 + k) * 27 + og * 9;  // uniform -> s_load
#pragma unroll
                for (int j = 0; j < 9; ++j) acc[j] = fmaf(wp[j], xv, acc[j]);
            }
        }
    }

    int hw = ((ty + row) << 7) + tx + col;
#pragma unroll
    for (int j = 0; j < 9; ++j) {
        int oc = og * 9 + j;
        atomicAdd(&cbuf[((b * 27 + oc) << 14) + hw], acc[j]);
    }
}

// Deformable gather + GEMM, software-pipelined.
// Grid: (HW/64, B). Block: 256 = 4 waves. Wave w owns o-channels [w*32, w*32+32), lane = pixel.
// Chunk = 4 channels (36 rows). Double-buffered lv; next chunk's x-loads issued into registers
// BEFORE the GEMM, combined + ds_written AFTER -> HBM/L2 latency hides under 1152 FMAs.
__global__ __launch_bounds__(256, 4) void k_deform(const float* __restrict__ x,
                                                   const float* __restrict__ cbuf,
                                                   const float* __restrict__ b_off,
                                                   const float* __restrict__ b_mod,
                                                   const float* __restrict__ w_t,
                                                   float* __restrict__ out) {
    __shared__ int   sp_off[9 * 4 * 64];    // byte offset of clamped (y,x) within one channel plane
    __shared__ float sp_w  [9 * 4 * 64];    // premultiplied mask*bilinear*valid
    __shared__ float lv[2][36 * 64];        // [buf][row within chunk][pixel]

    int tid = threadIdx.x;
    int b = blockIdx.y;
    int hwbase = blockIdx.x * 64;
    int lane = tid & 63;
    int wid = tid >> 6;

    // ---- Phase 1: sample descriptors for 64 pixels x 9 taps ----
    for (int i = tid; i < 576; i += 256) {
        int k = i >> 6, p = i & 63;
        int hw = hwbase + p;
        int h = hw >> 7, cc = hw & 127;
        const float* cb = cbuf + ((size_t)(b * 27) << 14);
        float oy = cb[((2 * k) << 14) + hw]     + b_off[2 * k];
        float ox = cb[((2 * k + 1) << 14) + hw] + b_off[2 * k + 1];
        float mr = cb[((18 + k) << 14) + hw]    + b_mod[k];
        float m  = 2.f / (1.f + expf(-mr));
        float py = (float)(h - 1 + k / 3) + oy;
        float px = (float)(cc - 1 + k % 3) + ox;
        float fy = floorf(py), fx = floorf(px);
        float wy1 = py - fy, wx1 = px - fx;
        int y0 = (int)fy, x0 = (int)fx;
#pragma unroll
        for (int dy = 0; dy < 2; ++dy)
#pragma unroll
            for (int dx = 0; dx < 2; ++dx) {
                int yy = y0 + dy, xx = x0 + dx;
                bool valid = (yy >= 0) && (yy < 128) && (xx >= 0) && (xx < 128);
                float wgt = m * (dy ? wy1 : 1.f - wy1) * (dx ? wx1 : 1.f - wx1);
                int yc = min(max(yy, 0), 127), xc = min(max(xx, 0), 127);
                int s = (k * 4 + dy * 2 + dx) * 64 + p;
                sp_off[s] = ((yc << 7) + xc) << 2;
                sp_w[s]   = valid ? wgt : 0.f;
            }
    }
    __syncthreads();

    f32x2 acc[16];
#pragma unroll
    for (int i = 0; i < 16; ++i) acc[i] = (f32x2)(0.f);

    const char* xbase = (const char*)x + ((size_t)b << 23);   // b*128*16384*4
    int obase = wid * 32;

    // ---- prologue: gather chunk 0 (channels wid) into lv[0] ----
    {
        const char* xc_ = xbase + ((size_t)wid << 16);        // channel plane, bytes
#pragma unroll
        for (int j = 0; j < 9; ++j) {
            int s = j * 256 + lane;
            float v = sp_w[s] * *(const float*)(xc_ + sp_off[s]);
            v = fmaf(sp_w[s + 64],  *(const float*)(xc_ + sp_off[s + 64]),  v);
            v = fmaf(sp_w[s + 128], *(const float*)(xc_ + sp_off[s + 128]), v);
            v = fmaf(sp_w[s + 192], *(const float*)(xc_ + sp_off[s + 192]), v);
            lv[0][(wid * 9 + j) * 64 + lane] = v;
        }
    }
    __syncthreads();

    int buf = 0;
    for (int chunk = 0; chunk < 32; ++chunk) {
        int cbase = chunk * 4;

        // step 1: ISSUE next chunk's 36 x-loads into registers (in flight during GEMM)
        float xv[36];
        if (chunk < 31) {
            const char* xc_ = xbase + ((size_t)(cbase + 4 + wid) << 16);
#pragma unroll
            for (int j = 0; j < 9; ++j) {
                int s = j * 256 + lane;
                xv[j * 4 + 0] = *(const float*)(xc_ + sp_off[s]);
                xv[j * 4 + 1] = *(const float*)(xc_ + sp_off[s + 64]);
                xv[j * 4 + 2] = *(const float*)(xc_ + sp_off[s + 128]);
                xv[j * 4 + 3] = *(const float*)(xc_ + sp_off[s + 192]);
            }
        }

        // step 2: GEMM on lv[buf]: acc[o] += w_t[cbase*9+r][obase+o] * lv[r][lane]
        const float* wrow = w_t + (size_t)(cbase * 9) * 128 + obase;
#pragma unroll 6
        for (int r = 0; r < 36; ++r) {
            float v = lv[buf][r * 64 + lane];
            f32x2 vv = {v, v};
            const f32x2* w2 = (const f32x2*)(wrow + (size_t)r * 128);  // wave-uniform -> s_load
#pragma unroll
            for (int i = 0; i < 16; ++i) acc[i] += w2[i] * vv;         // candidate v_pk_fma_f32
        }

        // step 3: combine arrived loads, write next buffer
        if (chunk < 31) {
#pragma unroll
            for (int j = 0; j < 9; ++j) {
                int s = j * 256 + lane;
                float v = sp_w[s] * xv[j * 4 + 0];
                v = fmaf(sp_w[s + 64],  xv[j * 4 + 1], v);
                v = fmaf(sp_w[s + 128], xv[j * 4 + 2], v);
                v = fmaf(sp_w[s + 192], xv[j * 4 + 3], v);
                lv[buf ^ 1][(wid * 9 + j) * 64 + lane] = v;
            }
        }
        __syncthreads();
        buf ^= 1;
    }

    // ---- write out: coalesced 64-wide rows; acc[i] = {o=obase+2i, o=obase+2i+1} ----
    size_t ob = ((size_t)(b * NO + obase) << 14) + hwbase + lane;
#pragma unroll
    for (int i = 0; i < 16; ++i) {
        out[ob + ((size_t)(2 * i) << 14)]     = acc[i].x;
        out[ob + ((size_t)(2 * i + 1) << 14)] = acc[i].y;
    }
}

extern "C" void kernel_launch(void* const* d_in, const int* in_sizes, int n_in,
                              void* d_out, int out_size, void* d_ws, size_t ws_size,
                              hipStream_t stream) {
    const float* x     = (const float*)d_in[0];
    const float* w_off = (const float*)d_in[1];
    const float* b_off = (const float*)d_in[2];
    const float* w_mod = (const float*)d_in[3];
    const float* b_mod = (const float*)d_in[4];
    const float* w_reg = (const float*)d_in[5];
    float* out = (float*)d_out;

    // workspace layout (floats): cbuf [4*27*16384] | w_t [1152*128] | wt_om [1152*27]
    float* cbuf  = (float*)d_ws;
    float* w_t   = cbuf + (size_t)NB * 27 * HWD;   // 1,769,472 floats
    float* wt_om = w_t + 1152 * 128;               // +147,456

    hipMemsetAsync(cbuf, 0, (size_t)NB * 27 * HWD * sizeof(float), stream);
    hipLaunchKernelGGL(k_transpose_wreg, dim3(576), dim3(256), 0, stream, w_reg, w_t);
    hipLaunchKernelGGL(k_transpose_wom,  dim3(122), dim3(256), 0, stream, w_off, w_mod, wt_om);
    hipLaunchKernelGGL(k_conv_om, dim3(8, 8, NB * 6), dim3(256), 0, stream, x, wt_om, cbuf);
    hipLaunchKernelGGL(k_deform, dim3(HWD / 64, NB), dim3(256), 0, stream,
                       x, cbuf, b_off, b_mod, w_t, out);
}

// Round 7
// 430.514 us; speedup vs baseline: 3.2169x; 3.2169x over previous
//
#include <hip/hip_runtime.h>
#include <math.h>

// Problem constants: B=4, C=128, O=128, H=W=128, k=3, K=9, pad=1, stride=1.
#define HWD 16384   // H*W
#define NB  4
#define NC  128
#define NO  128

typedef float  f32x4  __attribute__((ext_vector_type(4)));
typedef short  s16x8  __attribute__((ext_vector_type(8)));

// Split w_reg into bf16 hi/lo, laid out for MFMA A-fragments, K reordered tap-major.
// wA[s][o][kk]: slice s = kt*4 + cc (kt=tap 0..8, cc=channel-chunk 0..3), kk 0..31 -> c = cc*32+kk.
// value = w_reg[o][c][kt]  (w_reg flat: o*1152 + c*9 + kt)
__global__ void k_split_wreg(const float* __restrict__ w_reg,
                             short* __restrict__ wA_hi, short* __restrict__ wA_lo) {
    int i = blockIdx.x * 256 + threadIdx.x;          // 36*128*32 = 147456
    if (i >= 147456) return;
    int kk = i & 31, o = (i >> 5) & 127, s = i >> 12;
    int cc = s & 3, kt = s >> 2;
    int c  = cc * 32 + kk;
    float w = w_reg[o * 1152 + c * 9 + kt];
    unsigned ub = __builtin_bit_cast(unsigned, w);
    unsigned short h = (unsigned short)(ub >> 16);
    float wh = __builtin_bit_cast(float, (unsigned)h << 16);
    float r  = w - wh;
    unsigned short l = (unsigned short)(__builtin_bit_cast(unsigned, r) >> 16);
    wA_hi[i] = (short)h;
    wA_lo[i] = (short)l;
}

// wt_om[(c*9+k)*27 + oc]: oc 0..17 = offset weights, 18..26 = mask weights
__global__ void k_transpose_wom(const float* __restrict__ w_off, const float* __restrict__ w_mod,
                                float* __restrict__ wt_om) {
    int i = blockIdx.x * 256 + threadIdx.x;           // 31104 total
    if (i >= 1152 * 27) return;
    int oc = i % 27, r = i / 27;
    wt_om[i] = (oc < 18) ? w_off[oc * 1152 + r] : w_mod[(oc - 18) * 1152 + r];
}

// 3x3 conv producing 27 raw channels (no bias/sigmoid; applied by consumer).
// Grid: (8, 8, B*3*2). Block: 256 = 16x16 pixel tile. z -> (b, oc-group of 9, channel-half of 64).
// Accumulates into zeroed cbuf via fp32 atomicAdd (distinct addresses per block -> no contention).
__global__ __launch_bounds__(256) void k_conv_om(const float* __restrict__ x,
                                                 const float* __restrict__ wt_om,
                                                 float* __restrict__ cbuf) {
    __shared__ float xt[4 * 324];          // 4 channels x 18x18 halo tile
    int z = blockIdx.z;
    int b     = z / 6;
    int og    = z % 3;
    int chalf = (z % 6) / 3;
    int ty = blockIdx.y * 16, tx = blockIdx.x * 16;
    int tid = threadIdx.x;
    int row = tid >> 4, col = tid & 15;

    float acc[9];
#pragma unroll
    for (int j = 0; j < 9; ++j) acc[j] = 0.f;

    int cbeg = chalf * 64;
    for (int c0 = cbeg; c0 < cbeg + 64; c0 += 4) {
        __syncthreads();
        for (int i = tid; i < 1296; i += 256) {
            int ch = i / 324, rem = i - ch * 324;
            int ry = rem / 18, rx = rem - ry * 18;
            int gy = ty - 1 + ry, gx = tx - 1 + rx;
            float v = 0.f;
            if (gy >= 0 && gy < 128 && gx >= 0 && gx < 128)
                v = x[(((b << 7) + c0 + ch) << 14) + (gy << 7) + gx];
            xt[i] = v;
        }
        __syncthreads();
#pragma unroll
        for (int cc = 0; cc < 4; ++cc) {
#pragma unroll
            for (int k = 0; k < 9; ++k) {
                float xv = xt[cc * 324 + (row + k / 3) * 18 + (col + k % 3)];
                const float* wp = wt_om + ((c0 + cc) * 9 + k) * 27 + og * 9;  // uniform -> s_load
#pragma unroll
                for (int j = 0; j < 9; ++j) acc[j] = fmaf(wp[j], xv, acc[j]);
            }
        }
    }

    int hw = ((ty + row) << 7) + tx + col;
#pragma unroll
    for (int j = 0; j < 9; ++j) {
        int oc = og * 9 + j;
        atomicAdd(&cbuf[((b * 27 + oc) << 14) + hw], acc[j]);
    }
}

// Deformable gather + bf16-MFMA GEMM (3-pass split precision ~ fp32 accuracy).
// Grid: (HW/64, B). Block: 256 = 4 waves. Output tile: 128 o x 64 px; wave owns 32 o.
// K (=1152) reordered tap-major: slice s = kt*4+cc is 32 channels at one tap ->
// bilinear descriptors are per-(tap,px), reused across the 32 channels.
// Per slice: gather 32x64 vals -> bf16 hi/lo LDS tile -> 24 MFMA/wave. 1 barrier/slice, dbuf.
__global__ __launch_bounds__(256, 4) void k_deform(const float* __restrict__ x,
                                                   const float* __restrict__ cbuf,
                                                   const float* __restrict__ b_off,
                                                   const float* __restrict__ b_mod,
                                                   const short* __restrict__ wA_hi,
                                                   const short* __restrict__ wA_lo,
                                                   float* __restrict__ out) {
    __shared__ int   sp_off[9 * 4 * 64];     // [tap][corner][px] byte offset within channel plane
    __shared__ float sp_w  [9 * 4 * 64];     // premultiplied mask*bilinear*valid
    __shared__ short vt_hi[2][64 * 40];      // [buf][px][kk] stride 40 (16B-aligned rows, spread banks)
    __shared__ short vt_lo[2][64 * 40];

    int tid = threadIdx.x;
    int b = blockIdx.y;
    int hwbase = blockIdx.x * 64;
    int lane = tid & 63;
    int wid = tid >> 6;

    // ---- Phase 1: sample descriptors for 64 pixels x 9 taps ----
    for (int i = tid; i < 576; i += 256) {
        int k = i >> 6, p = i & 63;
        int hw = hwbase + p;
        int h = hw >> 7, cc = hw & 127;
        const float* cb = cbuf + ((size_t)(b * 27) << 14);
        float oy = cb[((2 * k) << 14) + hw]     + b_off[2 * k];
        float ox = cb[((2 * k + 1) << 14) + hw] + b_off[2 * k + 1];
        float mr = cb[((18 + k) << 14) + hw]    + b_mod[k];
        float m  = 2.f / (1.f + expf(-mr));
        float py = (float)(h - 1 + k / 3) + oy;
        float px = (float)(cc - 1 + k % 3) + ox;
        float fy = floorf(py), fx = floorf(px);
        float wy1 = py - fy, wx1 = px - fx;
        int y0 = (int)fy, x0 = (int)fx;
#pragma unroll
        for (int dy = 0; dy < 2; ++dy)
#pragma unroll
            for (int dx = 0; dx < 2; ++dx) {
                int yy = y0 + dy, xx = x0 + dx;
                bool valid = (yy >= 0) && (yy < 128) && (xx >= 0) && (xx < 128);
                float wgt = m * (dy ? wy1 : 1.f - wy1) * (dx ? wx1 : 1.f - wx1);
                int yc = min(max(yy, 0), 127), xc = min(max(xx, 0), 127);
                int s = (k * 4 + dy * 2 + dx) * 64 + p;
                sp_off[s] = ((yc << 7) + xc) << 2;
                sp_w[s]   = valid ? wgt : 0.f;
            }
    }
    __syncthreads();

    f32x4 acc0[4], acc1[4];                  // [px-tile], o-tile 0 and 1 for this wave
#pragma unroll
    for (int i = 0; i < 4; ++i) { acc0[i] = (f32x4)(0.f); acc1[i] = (f32x4)(0.f); }

    const char* xbase = (const char*)x + ((size_t)b << 23);   // b*128*16384*4 bytes
    int gpx  = tid & 63;                     // gather: pixel this thread fills
    int kk0  = (tid >> 6) << 3;              // gather: 8 consecutive kk
    int albase = (wid * 32 + (lane & 15)) * 32 + ((lane >> 4) << 3);   // A-frag offset (o-tile 0)
    int blds   = (lane & 15) * 40 + ((lane >> 4) << 3);                // B-frag LDS elem offset

    int buf = 0;
    for (int kt = 0; kt < 9; ++kt) {
        // hoist this tap's 4 corner descriptors (per-thread scalars, reused for 4 slices)
        int so = kt * 256 + gpx;
        int   o0 = sp_off[so], o1 = sp_off[so + 64], o2 = sp_off[so + 128], o3 = sp_off[so + 192];
        float s0 = sp_w[so],   s1 = sp_w[so + 64],   s2 = sp_w[so + 128],  s3 = sp_w[so + 192];

        for (int cc = 0; cc < 4; ++cc) {
            int s = kt * 4 + cc;

            // ---- gather 8 channels for (gpx, kk0..kk0+7), split to bf16 hi/lo ----
            s16x8 hi8, lo8;
#pragma unroll
            for (int i = 0; i < 8; ++i) {
                const char* xp = xbase + ((size_t)(cc * 32 + kk0 + i) << 16);
                float v = s0 * *(const float*)(xp + o0);
                v = fmaf(s1, *(const float*)(xp + o1), v);
                v = fmaf(s2, *(const float*)(xp + o2), v);
                v = fmaf(s3, *(const float*)(xp + o3), v);
                unsigned ub = __builtin_bit_cast(unsigned, v);
                unsigned short h = (unsigned short)(ub >> 16);
                float vh = __builtin_bit_cast(float, (unsigned)h << 16);
                float rr = v - vh;
                unsigned short l = (unsigned short)(__builtin_bit_cast(unsigned, rr) >> 16);
                hi8[i] = (short)h;
                lo8[i] = (short)l;
            }
            *(s16x8*)&vt_hi[buf][gpx * 40 + kk0] = hi8;
            *(s16x8*)&vt_lo[buf][gpx * 40 + kk0] = lo8;

            __syncthreads();   // tile ready (single barrier per slice; dbuf makes it race-free)

            // ---- MFMA: D[o][px] += A[o][k] * B[k][px], 3-pass hi/lo ----
            const s16x8* pah = (const s16x8*)(wA_hi + s * 4096 + albase);
            const s16x8* pal = (const s16x8*)(wA_lo + s * 4096 + albase);
            s16x8 a_h0 = pah[0], a_h1 = pah[64];    // +16 o = 512 shorts = 64 x s16x8
            s16x8 a_l0 = pal[0], a_l1 = pal[64];
#pragma unroll
            for (int pt = 0; pt < 4; ++pt) {
                s16x8 b_h = *(const s16x8*)&vt_hi[buf][pt * 640 + blds];
                s16x8 b_l = *(const s16x8*)&vt_lo[buf][pt * 640 + blds];
                acc0[pt] = __builtin_amdgcn_mfma_f32_16x16x32_bf16(a_h0, b_h, acc0[pt], 0, 0, 0);
                acc0[pt] = __builtin_amdgcn_mfma_f32_16x16x32_bf16(a_h0, b_l, acc0[pt], 0, 0, 0);
                acc0[pt] = __builtin_amdgcn_mfma_f32_16x16x32_bf16(a_l0, b_h, acc0[pt], 0, 0, 0);
                acc1[pt] = __builtin_amdgcn_mfma_f32_16x16x32_bf16(a_h1, b_h, acc1[pt], 0, 0, 0);
                acc1[pt] = __builtin_amdgcn_mfma_f32_16x16x32_bf16(a_h1, b_l, acc1[pt], 0, 0, 0);
                acc1[pt] = __builtin_amdgcn_mfma_f32_16x16x32_bf16(a_l1, b_h, acc1[pt], 0, 0, 0);
            }
            buf ^= 1;
        }
    }

    // ---- write out: C/D layout col=lane&15 (px), row=(lane>>4)*4+j (o) ----
    int q = lane >> 4, pcol = lane & 15;
#pragma unroll
    for (int pt = 0; pt < 4; ++pt) {
#pragma unroll
        for (int j = 0; j < 4; ++j) {
            int o0_ = wid * 32 + q * 4 + j;
            int o1_ = o0_ + 16;
            int px  = pt * 16 + pcol;
            out[((size_t)(b * NO + o0_) << 14) + hwbase + px] = acc0[pt][j];
            out[((size_t)(b * NO + o1_) << 14) + hwbase + px] = acc1[pt][j];
        }
    }
}

extern "C" void kernel_launch(void* const* d_in, const int* in_sizes, int n_in,
                              void* d_out, int out_size, void* d_ws, size_t ws_size,
                              hipStream_t stream) {
    const float* x     = (const float*)d_in[0];
    const float* w_off = (const float*)d_in[1];
    const float* b_off = (const float*)d_in[2];
    const float* w_mod = (const float*)d_in[3];
    const float* b_mod = (const float*)d_in[4];
    const float* w_reg = (const float*)d_in[5];
    float* out = (float*)d_out;

    // ws layout: cbuf f32[4*27*16384] | wt_om f32[31104] | wA_hi s16[147456] | wA_lo s16[147456]
    float* cbuf  = (float*)d_ws;
    float* wt_om = cbuf + (size_t)NB * 27 * HWD;       // 1,769,472 floats
    short* wA_hi = (short*)(wt_om + 31104);
    short* wA_lo = wA_hi + 147456;

    hipMemsetAsync(cbuf, 0, (size_t)NB * 27 * HWD * sizeof(float), stream);
    hipLaunchKernelGGL(k_split_wreg,    dim3(576), dim3(256), 0, stream, w_reg, wA_hi, wA_lo);
    hipLaunchKernelGGL(k_transpose_wom, dim3(122), dim3(256), 0, stream, w_off, w_mod, wt_om);
    hipLaunchKernelGGL(k_conv_om, dim3(8, 8, NB * 6), dim3(256), 0, stream, x, wt_om, cbuf);
    hipLaunchKernelGGL(k_deform, dim3(HWD / 64, NB), dim3(256), 0, stream,
                       x, cbuf, b_off, b_mod, wA_hi, wA_lo, out);
}